// Round 1
// baseline (84.427 us; speedup 1.0000x reference)
//
#include <hip/hip_runtime.h>

// modReLU: out = relu(|x|+b) * x/|x| for x != 0, else x (which is 0).
// Elementwise, memory-bound. float4 vectorized, grid-stride.

__global__ void modrelu_kernel(const float4* __restrict__ xre,
                               const float4* __restrict__ xim,
                               const float4* __restrict__ bias,   // 32 float4 (C=128)
                               float4* __restrict__ out_re,
                               float4* __restrict__ out_im,
                               int nvec) {
    int stride = gridDim.x * blockDim.x;
    for (int i = blockIdx.x * blockDim.x + threadIdx.x; i < nvec; i += stride) {
        float4 re = xre[i];
        float4 im = xim[i];
        float4 b  = bias[i & 31];   // C/4 = 32 vecs per row; rows aligned

        float4 ore, oim;
        {
            float r = sqrtf(re.x * re.x + im.x * im.x);
            float s = (r > 0.0f) ? fmaxf(r + b.x, 0.0f) / r : 0.0f;
            ore.x = s * re.x; oim.x = s * im.x;
        }
        {
            float r = sqrtf(re.y * re.y + im.y * im.y);
            float s = (r > 0.0f) ? fmaxf(r + b.y, 0.0f) / r : 0.0f;
            ore.y = s * re.y; oim.y = s * im.y;
        }
        {
            float r = sqrtf(re.z * re.z + im.z * im.z);
            float s = (r > 0.0f) ? fmaxf(r + b.z, 0.0f) / r : 0.0f;
            ore.z = s * re.z; oim.z = s * im.z;
        }
        {
            float r = sqrtf(re.w * re.w + im.w * im.w);
            float s = (r > 0.0f) ? fmaxf(r + b.w, 0.0f) / r : 0.0f;
            ore.w = s * re.w; oim.w = s * im.w;
        }

        out_re[i] = ore;
        out_im[i] = oim;
    }
}

extern "C" void kernel_launch(void* const* d_in, const int* in_sizes, int n_in,
                              void* d_out, int out_size, void* d_ws, size_t ws_size,
                              hipStream_t stream) {
    const float* x_re = (const float*)d_in[0];
    const float* x_im = (const float*)d_in[1];
    const float* bias = (const float*)d_in[2];
    float* out = (float*)d_out;

    const int total = in_sizes[0];        // N*C = 25,600,000
    const int nvec  = total / 4;          // 6,400,000 float4s

    float* out_re = out;                  // [N, C]
    float* out_im = out + total;          // [N, C]

    const int block = 256;
    int grid = (nvec + block - 1) / block;
    if (grid > 2048) grid = 2048;         // 256 CU x 8 blocks, grid-stride rest

    modrelu_kernel<<<grid, block, 0, stream>>>(
        (const float4*)x_re, (const float4*)x_im, (const float4*)bias,
        (float4*)out_re, (float4*)out_im, nvec);
}

// Round 3
// 75.092 us; speedup vs baseline: 1.1243x; 1.1243x over previous
//
#include <hip/hip_runtime.h>

// modReLU: out = relu(|x|+b) * x/|x| for x != 0, else x (which is 0).
// Elementwise, memory-bound. 16B vectorized, grid-stride,
// non-temporal loads/stores (data is touched exactly once).

typedef float fvec4 __attribute__((ext_vector_type(4)));   // native vector for nontemporal builtins

__global__ void modrelu_kernel(const fvec4* __restrict__ xre,
                               const fvec4* __restrict__ xim,
                               const fvec4* __restrict__ bias,   // 32 vecs (C=128)
                               fvec4* __restrict__ out_re,
                               fvec4* __restrict__ out_im,
                               int nvec) {
    int stride = gridDim.x * blockDim.x;
    for (int i = blockIdx.x * blockDim.x + threadIdx.x; i < nvec; i += stride) {
        fvec4 re = __builtin_nontemporal_load(&xre[i]);
        fvec4 im = __builtin_nontemporal_load(&xim[i]);
        fvec4 b  = bias[i & 31];   // C/4 = 32 vecs per row; L1/L2-resident

        fvec4 ore, oim;
        #pragma unroll
        for (int j = 0; j < 4; ++j) {
            float d   = re[j] * re[j] + im[j] * im[j];
            float irs = (d > 0.0f) ? __frsqrt_rn(d) : 0.0f;
            float r   = d * irs;                        // |x|
            float s   = fmaxf(r + b[j], 0.0f) * irs;    // relu(r+b)/r
            ore[j] = s * re[j];
            oim[j] = s * im[j];
        }

        __builtin_nontemporal_store(ore, &out_re[i]);
        __builtin_nontemporal_store(oim, &out_im[i]);
    }
}

extern "C" void kernel_launch(void* const* d_in, const int* in_sizes, int n_in,
                              void* d_out, int out_size, void* d_ws, size_t ws_size,
                              hipStream_t stream) {
    const float* x_re = (const float*)d_in[0];
    const float* x_im = (const float*)d_in[1];
    const float* bias = (const float*)d_in[2];
    float* out = (float*)d_out;

    const int total = in_sizes[0];        // N*C = 25,600,000
    const int nvec  = total / 4;          // 6,400,000 vecs

    float* out_re = out;                  // [N, C]
    float* out_im = out + total;          // [N, C]

    const int block = 256;
    int grid = (nvec + block - 1) / block;
    if (grid > 2048) grid = 2048;         // 256 CU x 8 blocks, grid-stride rest

    modrelu_kernel<<<grid, block, 0, stream>>>(
        (const fvec4*)x_re, (const fvec4*)x_im, (const fvec4*)bias,
        (fvec4*)out_re, (fvec4*)out_im, nvec);
}